// Round 12
// baseline (106.109 us; speedup 1.0000x reference)
//
#include <hip/hip_runtime.h>

// MultiScaleRetention on MI355X (gfx950)
// B=2, L=2048, D=1024, H=16, hd=64. fp32 in/out, bf16 MFMA internally.
//
// ws layout (ushort elems), 40 MB total:
//   qf[4M] | kf[4M] | vf[4M] | ret/xb[4M] (aliased) | wqb|wkb|wvb|wob [1M each]
//   qf,kf: fragment-linear [(b*16+h)*64+sb][kt:4][lane:64][8]
//   kf is PRE-SCALED by gamma_h^(31-(s&31)) (decay column factor folded in)
//   vf:    fragment-linear [(b*16+h)*64+sb][i:4][lane:64][8]
//   ret,xb: [B*L][1024] row-major bf16

typedef __attribute__((ext_vector_type(8))) short bf16x8;
typedef __attribute__((ext_vector_type(4))) float f32x4;
typedef __attribute__((ext_vector_type(16))) float f32x16;
typedef __attribute__((ext_vector_type(4))) unsigned short u16x4;
typedef __attribute__((ext_vector_type(8))) unsigned short u16x8;
typedef __attribute__((ext_vector_type(4))) unsigned int u32x4;

__device__ inline unsigned short f2bf(float f) {
    unsigned int u;
    __builtin_memcpy(&u, &f, 4);
    u += 0x7fffu + ((u >> 16) & 1u);
    return (unsigned short)(u >> 16);
}

__device__ inline f32x4 mfma16(bf16x8 a, bf16x8 b, f32x4 c) {
    return __builtin_amdgcn_mfma_f32_16x16x32_bf16(a, b, c, 0, 0, 0);
}
__device__ inline f32x16 mfma32(bf16x8 a, bf16x8 b, f32x16 c) {
    return __builtin_amdgcn_mfma_f32_32x32x16_bf16(a, b, c, 0, 0, 0);
}

__device__ inline void gl16(const unsigned short* g, unsigned short* l) {
    __builtin_amdgcn_global_load_lds(
        (const __attribute__((address_space(1))) unsigned int*)g,
        (__attribute__((address_space(3))) unsigned int*)l,
        16, 0, 0);
}

__device__ inline unsigned cvtpk(float lo, float hi) {
    unsigned r;
    asm("v_cvt_pk_bf16_f32 %0, %1, %2" : "=v"(r) : "v"(lo), "v"(hi));
    return r;
}

// ---------------------------------------------------------------------------
// Kernel 0: f32 -> bf16 conversion of x and the four weight matrices.
// ---------------------------------------------------------------------------
__global__ __launch_bounds__(256) void convert_bf16(
    const float* __restrict__ x,
    const float* __restrict__ wq, const float* __restrict__ wk,
    const float* __restrict__ wv, const float* __restrict__ wo,
    unsigned short* __restrict__ xb,
    unsigned short* __restrict__ wqb, unsigned short* __restrict__ wkb,
    unsigned short* __restrict__ wvb, unsigned short* __restrict__ wob)
{
    int cid = blockIdx.x * 256 + threadIdx.x;
    #pragma unroll
    for (int it = 0; it < 4; ++it, cid += 262144) {
        const float* src;
        unsigned short* dst;
        size_t off;
        if (cid < 524288) {
            src = x; dst = xb; off = (size_t)cid * 8;
        } else {
            const int t = cid - 524288;
            const int seg = t >> 17;
            off = (size_t)(t & 131071) * 8;
            src = seg == 0 ? wq : seg == 1 ? wk : seg == 2 ? wv : wo;
            dst = seg == 0 ? wqb : seg == 1 ? wkb : seg == 2 ? wvb : wob;
        }
        f32x4 a = *(const f32x4*)(src + off);
        f32x4 b = *(const f32x4*)(src + off + 4);
        u32x4 v = { cvtpk(a[0], a[1]), cvtpk(a[2], a[3]),
                    cvtpk(b[0], b[1]), cvtpk(b[2], b[3]) };
        *(u32x4*)(dst + off) = v;
    }
}

// ---------------------------------------------------------------------------
// Kernel 1: QKV projections. Epilogue writes MFMA-fragment-linear layouts;
// K is pre-scaled by gamma_h^(31-(s&31)) so retention's decay needs only the
// per-lane rowf factor.
// ---------------------------------------------------------------------------
__global__ __launch_bounds__(256) void qkv_bf16(
    const unsigned short* __restrict__ xb,
    const unsigned short* __restrict__ wqb, const unsigned short* __restrict__ wkb,
    const unsigned short* __restrict__ wvb, const float* __restrict__ gammas,
    unsigned short* __restrict__ qfr, unsigned short* __restrict__ kfr,
    unsigned short* __restrict__ vfr)
{
    __shared__ unsigned short sR[128 * 64];
    __shared__ unsigned short sL[128 * 64];

    const int z = blockIdx.z;
    const unsigned short* W = (z == 0) ? wqb : (z == 1) ? wkb : wvb;
    const unsigned short* Rs = (z < 2) ? xb : W;
    const unsigned short* Ls = (z < 2) ? W : xb;
    const int rblk = (z < 2) ? blockIdx.x : blockIdx.y;
    const int lblk = (z < 2) ? blockIdx.y : blockIdx.x;

    const int tid = threadIdx.x;
    const int l = tid & 63, w = tid >> 6;
    const int lrow = l & 15, koff4 = (l >> 4) * 4;
    const int swz = lrow & 7;
    const int wrow = (w >> 1) * 64, wcol = (w & 1) * 64;

    f32x4 acc[4][4] = {};

    const int srow = w * 32 + (l >> 3);
    const int scol = ((l & 7) ^ ((l >> 3) & 7)) * 8;
    const unsigned short* gR = Rs + (size_t)(rblk * 128 + srow) * 1024 + scol;
    const unsigned short* gL = Ls + (size_t)(lblk * 128 + srow) * 1024 + scol;
    unsigned short* lRb = sR + (w * 32) * 64;
    unsigned short* lLb = sL + (w * 32) * 64;

    for (int kk = 0; kk < 1024; kk += 64) {
        #pragma unroll
        for (int p = 0; p < 4; ++p) {
            gl16(gR + (size_t)p * 8 * 1024 + kk, lRb + p * 512);
            gl16(gL + (size_t)p * 8 * 1024 + kk, lLb + p * 512);
        }
        __syncthreads();
        #pragma unroll
        for (int kt = 0; kt < 2; ++kt) {
            bf16x8 aL[4], bR[4];
            #pragma unroll
            for (int f = 0; f < 4; ++f) {
                const int co = ((kt * 4 + (l >> 4)) ^ swz) * 8;
                aL[f] = *(const bf16x8*)&sL[(wcol + f * 16 + lrow) * 64 + co];
                bR[f] = *(const bf16x8*)&sR[(wrow + f * 16 + lrow) * 64 + co];
            }
            #pragma unroll
            for (int af = 0; af < 4; ++af)
                #pragma unroll
                for (int bf = 0; bf < 4; ++bf)
                    acc[af][bf] = mfma16(aL[af], bR[bf], acc[af][bf]);
        }
        __syncthreads();
    }

    #pragma unroll
    for (int af = 0; af < 4; ++af) {
        #pragma unroll
        for (int bf = 0; bf < 4; ++bf) {
            const int m = rblk * 128 + wrow + bf * 16 + lrow;
            const int n0 = lblk * 128 + wcol + af * 16 + koff4;
            f32x4 v = acc[af][bf];
            if (z == 1) {
                // fold decay column factor into K: * gamma_h^(31 - (s&31))
                const float lgh = log2f(gammas[(n0 >> 6) & 15]);
                const float sf = exp2f(lgh * (float)(31 - (m & 31)));
                v[0] *= sf; v[1] *= sf; v[2] *= sf; v[3] *= sf;
            }
            unsigned p0 = cvtpk(v[0], v[1]), p1 = cvtpk(v[2], v[3]);
            u16x4 val = { (unsigned short)(p0 & 0xffff), (unsigned short)(p0 >> 16),
                          (unsigned short)(p1 & 0xffff), (unsigned short)(p1 >> 16) };
            if (z < 2) {
                const int bq = m >> 11, s = m & 2047;
                const int h2 = n0 >> 6, dd = n0 & 63;
                const size_t addr = (size_t)((bq * 16 + h2) * 64 + (s >> 5)) * 2048
                                  + (size_t)(dd >> 4) * 512 + (size_t)((dd >> 3) & 1) * 256
                                  + (size_t)(s & 31) * 8 + (dd & 7);
                unsigned short* dst = z ? kfr : qfr;
                *(u16x4*)(dst + addr) = val;
            } else {
                const int h2 = m >> 6, dd = m & 63;
                const int bq = n0 >> 11, t = n0 & 2047;
                const size_t addr = (size_t)((bq * 16 + h2) * 64 + (t >> 5)) * 2048
                                  + (size_t)((dd >> 5) * 2 + ((t >> 4) & 1)) * 512
                                  + (size_t)((t >> 3) & 1) * 256
                                  + (size_t)(dd & 31) * 8 + (t & 7);
                *(u16x4*)(vfr + addr) = val;
            }
        }
    }
}

// ---------------------------------------------------------------------------
// Kernel 2: retention with per-wave async LDS pipeline (T4 counted-vmcnt).
// Block = 4 waves on one (bh,tw); wave w owns a contiguous quarter of the
// s-window. Each wave stages its K/V s-blocks via global_load_lds into a
// PRIVATE LDS double-buffer (no barrier, no VGPR dependency); counted
// s_waitcnt vmcnt(8) keeps the next stage in flight. Chain per iter becomes
// ds_read-class (~120cy) instead of L2-class (~600cy).
// Final reduce reuses the staging LDS after a barrier.
// ---------------------------------------------------------------------------
__global__ __launch_bounds__(256) void retention_lds(
    const unsigned short* __restrict__ qfr, const unsigned short* __restrict__ kfr,
    const unsigned short* __restrict__ vfr, const float* __restrict__ gammas,
    unsigned short* __restrict__ ret)
{
    __shared__ unsigned short kv[4][2][4096];   // [wave][buf][K:2048|V:2048] = 64 KB

    const int bid = blockIdx.x;
    const int xcd = bid & 7;
    const int r_ = bid >> 3;                     // 0..255
    const int p = r_ >> 2;                       // 0..63, heavy tiles first
    const int m = ((r_ & 3) + (r_ >> 5)) & 3;    // bijective; cycles heads per CU
    const int tw = 63 - p;
    const int b = m >> 1;
    const int pi = b ? (7 - xcd) : xcd;
    const int h = (m & 1) ? (15 - pi) : pi;
    const float lg = log2f(gammas[h]);           // < 0
    const int cut_i = (int)(45.0f / (-lg));
    const float gi32 = exp2f(-32.0f * lg);       // gamma^-32

    const int tid = threadIdx.x;
    const int l = tid & 63, w = tid >> 6;
    const int l31 = l & 31, hi = l >> 5;
    const int tw0 = tw << 5;
    const int tq = tw0 + l31;

    const size_t hbase = (size_t)((b * 16 + h) * 64) * 2048;
    const unsigned short* qfb = qfr + hbase + l * 8;
    const unsigned short* kfb = kfr + hbase + l * 8;
    const unsigned short* vfb = vfr + hbase + l * 8;

    // Q fragments (B operand: n=l31 -> t)
    bf16x8 qf[4];
    #pragma unroll
    for (int kt = 0; kt < 4; ++kt)
        qf[kt] = *(const bf16x8*)(qfb + (size_t)tw * 2048 + kt * 512);

    int sb_lo = tw0 - 31 - cut_i;
    sb_lo = (sb_lo <= 0) ? 0 : (sb_lo >> 5);

    const int n = tw - sb_lo + 1;
    const int chunk = (n + 3) >> 2;
    const int my_lo = sb_lo + w * chunk;
    int my_hi = my_lo + chunk;
    if (my_hi > tw + 1) my_hi = tw + 1;

    unsigned short* slot[2] = { &kv[w][0][0], &kv[w][1][0] };

    auto stage = [&](int sb, unsigned short* s) {
        const unsigned short* kp = kfb + (size_t)sb * 2048;
        const unsigned short* vp = vfb + (size_t)sb * 2048;
        #pragma unroll
        for (int t = 0; t < 4; ++t) gl16(kp + t * 512, s + t * 512);
        #pragma unroll
        for (int t = 0; t < 4; ++t) gl16(vp + t * 512, s + 2048 + t * 512);
    };

    f32x16 acc0 = {}, acc1 = {};

    if (my_lo < my_hi) {
        float rowf = 0.125f * exp2f((float)(tq - (my_lo << 5) - 31) * lg);
        stage(my_lo, slot[0]);
        if (my_lo + 1 < my_hi) stage(my_lo + 1, slot[1]);

        for (int sb = my_lo; sb < my_hi; ++sb) {
            unsigned short* cur = slot[(sb - my_lo) & 1];
            // counted wait: stage(sb) done; stage(sb+1) stays in flight
            if (sb + 1 < my_hi) asm volatile("s_waitcnt vmcnt(8)" ::: "memory");
            else                asm volatile("s_waitcnt vmcnt(0)" ::: "memory");
            __builtin_amdgcn_sched_barrier(0);

            bf16x8 kc[4], vc[4];
            #pragma unroll
            for (int kt = 0; kt < 4; ++kt)
                kc[kt] = *(const bf16x8*)(cur + kt * 512 + l * 8);
            #pragma unroll
            for (int i = 0; i < 4; ++i)
                vc[i] = *(const bf16x8*)(cur + 2048 + i * 512 + l * 8);

            // QK^T swapped: A=K (m=s), B=Q (n=t). D: col=t=l31, row=s=crow(r)
            f32x16 sc = {};
            __builtin_amdgcn_s_setprio(1);
            #pragma unroll
            for (int kt = 0; kt < 4; ++kt) sc = mfma32(kc[kt], qf[kt], sc);
            __builtin_amdgcn_s_setprio(0);

            float wv_[16];
            if (sb == tw) {            // wave-uniform: diag tile
                const int dtq = tq - (sb << 5);
                #pragma unroll
                for (int r = 0; r < 16; ++r) {
                    const int crow = (r & 3) + (hi << 2) + ((r >> 2) << 3);
                    float t_ = sc[r] * rowf;
                    wv_[r] = (dtq >= crow) ? t_ : 0.0f;
                }
            } else {
                #pragma unroll
                for (int r = 0; r < 16; ++r)
                    wv_[r] = sc[r] * rowf;
            }
            unsigned pk_[8];
            #pragma unroll
            for (int i = 0; i < 8; ++i) pk_[i] = cvtpk(wv_[2 * i], wv_[2 * i + 1]);
            asm("v_permlane32_swap_b32 %0, %1" : "+v"(pk_[0]), "+v"(pk_[2]));
            asm("v_permlane32_swap_b32 %0, %1" : "+v"(pk_[1]), "+v"(pk_[3]));
            asm("v_permlane32_swap_b32 %0, %1" : "+v"(pk_[4]), "+v"(pk_[6]));
            asm("v_permlane32_swap_b32 %0, %1" : "+v"(pk_[5]), "+v"(pk_[7]));
            u32x4 f0v = { pk_[0], pk_[1], pk_[2], pk_[3] };
            u32x4 f1v = { pk_[4], pk_[5], pk_[6], pk_[7] };
            const bf16x8 pa0 = __builtin_bit_cast(bf16x8, f0v);
            const bf16x8 pa1 = __builtin_bit_cast(bf16x8, f1v);
            // PV: A=P (m=t), B=V (n=d, k=s)
            __builtin_amdgcn_s_setprio(1);
            acc0 = mfma32(pa0, vc[0], acc0);
            acc0 = mfma32(pa1, vc[1], acc0);
            acc1 = mfma32(pa0, vc[2], acc1);
            acc1 = mfma32(pa1, vc[3], acc1);
            __builtin_amdgcn_s_setprio(0);
            rowf *= gi32;

            // restage current slot with sb+2 (after all LDS reads drained)
            if (sb + 2 < my_hi) {
                asm volatile("s_waitcnt lgkmcnt(0)" ::: "memory");
                __builtin_amdgcn_sched_barrier(0);
                stage(sb + 2, cur);
            }
        }
    }

    // reduce: reuse kv LDS as float scratch (all gl16 drained before loop exit)
    __syncthreads();
    float* red = (float*)&kv[0][0][0];   // need 24 KB of the 64 KB
    if (w > 0) {
        #pragma unroll
        for (int r = 0; r < 16; ++r) {
            red[(w - 1) * 2048 + r * 64 + l]        = acc0[r];
            red[(w - 1) * 2048 + (r + 16) * 64 + l] = acc1[r];
        }
    }
    __syncthreads();
    if (w == 0) {
        #pragma unroll
        for (int jj = 0; jj < 3; ++jj)
            #pragma unroll
            for (int r = 0; r < 16; ++r) {
                acc0[r] += red[jj * 2048 + r * 64 + l];
                acc1[r] += red[jj * 2048 + (r + 16) * 64 + l];
            }
        #pragma unroll
        for (int r = 0; r < 16; ++r) {
            const int tl = (r & 3) + (hi << 2) + ((r >> 2) << 3);
            unsigned short* dst = ret + (size_t)(b * 2048 + tw0 + tl) * 1024 + h * 64 + l31;
            dst[0]  = f2bf(acc0[r]);
            dst[32] = f2bf(acc1[r]);
        }
    }
}

// ---------------------------------------------------------------------------
// Kernel 3: out = ret @ wo.T, bf16 in / f32 out, same swizzled m97 structure.
// ---------------------------------------------------------------------------
__global__ __launch_bounds__(256) void out_bf16(
    const unsigned short* __restrict__ ret, const unsigned short* __restrict__ wob,
    float* __restrict__ out)
{
    __shared__ unsigned short sR[128 * 64];
    __shared__ unsigned short sL[128 * 64];

    const int rblk = blockIdx.x;
    const int lblk = blockIdx.y;

    const int tid = threadIdx.x;
    const int l = tid & 63, w = tid >> 6;
    const int lrow = l & 15, koff4 = (l >> 4) * 4;
    const int swz = lrow & 7;
    const int wrow = (w >> 1) * 64, wcol = (w & 1) * 64;

    f32x4 acc[4][4] = {};

    const int srow = w * 32 + (l >> 3);
    const int scol = ((l & 7) ^ ((l >> 3) & 7)) * 8;
    const unsigned short* gR = ret + (size_t)(rblk * 128 + srow) * 1024 + scol;
    const unsigned short* gL = wob + (size_t)(lblk * 128 + srow) * 1024 + scol;
    unsigned short* lRb = sR + (w * 32) * 64;
    unsigned short* lLb = sL + (w * 32) * 64;

    for (int kk = 0; kk < 1024; kk += 64) {
        #pragma unroll
        for (int p = 0; p < 4; ++p) {
            gl16(gR + (size_t)p * 8 * 1024 + kk, lRb + p * 512);
            gl16(gL + (size_t)p * 8 * 1024 + kk, lLb + p * 512);
        }
        __syncthreads();
        #pragma unroll
        for (int kt = 0; kt < 2; ++kt) {
            bf16x8 aL[4], bR[4];
            #pragma unroll
            for (int f = 0; f < 4; ++f) {
                const int co = ((kt * 4 + (l >> 4)) ^ swz) * 8;
                aL[f] = *(const bf16x8*)&sL[(wcol + f * 16 + lrow) * 64 + co];
                bR[f] = *(const bf16x8*)&sR[(wrow + f * 16 + lrow) * 64 + co];
            }
            #pragma unroll
            for (int af = 0; af < 4; ++af)
                #pragma unroll
                for (int bf = 0; bf < 4; ++bf)
                    acc[af][bf] = mfma16(aL[af], bR[bf], acc[af][bf]);
        }
        __syncthreads();
    }

    #pragma unroll
    for (int af = 0; af < 4; ++af)
        #pragma unroll
        for (int bf = 0; bf < 4; ++bf) {
            const int m = rblk * 128 + wrow + bf * 16 + lrow;
            const int n0 = lblk * 128 + wcol + af * 16 + koff4;
            *(f32x4*)(out + (size_t)m * 1024 + n0) = acc[af][bf];
        }
}

extern "C" void kernel_launch(void* const* d_in, const int* in_sizes, int n_in,
                              void* d_out, int out_size, void* d_ws, size_t ws_size,
                              hipStream_t stream) {
    const float* x      = (const float*)d_in[0];
    const float* wq     = (const float*)d_in[1];
    const float* wk     = (const float*)d_in[2];
    const float* wv     = (const float*)d_in[3];
    const float* wo     = (const float*)d_in[4];
    const float* gammas = (const float*)d_in[5];
    float* out = (float*)d_out;

    unsigned short* ws = (unsigned short*)d_ws;
    unsigned short* qf  = ws;
    unsigned short* kf  = ws + (size_t)4 * 1024 * 1024;
    unsigned short* vf  = ws + (size_t)8 * 1024 * 1024;
    unsigned short* ret = ws + (size_t)12 * 1024 * 1024;   // also xb (dead after qkv)
    unsigned short* xb  = ret;
    unsigned short* wqb = ws + (size_t)16 * 1024 * 1024;
    unsigned short* wkb = ws + (size_t)17 * 1024 * 1024;
    unsigned short* wvb = ws + (size_t)18 * 1024 * 1024;
    unsigned short* wob = ws + (size_t)19 * 1024 * 1024;

    convert_bf16<<<1024, 256, 0, stream>>>(x, wq, wk, wv, wo, xb, wqb, wkb, wvb, wob);
    qkv_bf16<<<dim3(32, 8, 3), 256, 0, stream>>>(xb, wqb, wkb, wvb, gammas, qf, kf, vf);
    retention_lds<<<2048, 256, 0, stream>>>(qf, kf, vf, gammas, ret);
    out_bf16<<<dim3(32, 8), 256, 0, stream>>>(ret, wob, out);
}

// Round 13
// 96.817 us; speedup vs baseline: 1.0960x; 1.0960x over previous
//
#include <hip/hip_runtime.h>

// MultiScaleRetention on MI355X (gfx950)
// B=2, L=2048, D=1024, H=16, hd=64. fp32 in/out, bf16 MFMA internally.
//
// ws layout (ushort elems), 40 MB total:
//   qf[4M] | kf[4M] | vf[4M] | ret/xb[4M] (aliased) | wqb|wkb|wvb|wob [1M each]
//   qf,kf: fragment-linear [(b*16+h)*64+sb][kt:4][lane:64][8]
//   vf:    fragment-linear [(b*16+h)*64+sb][i:4][lane:64][8]
//   ret,xb: [B*L][1024] row-major bf16

typedef __attribute__((ext_vector_type(8))) short bf16x8;
typedef __attribute__((ext_vector_type(4))) float f32x4;
typedef __attribute__((ext_vector_type(16))) float f32x16;
typedef __attribute__((ext_vector_type(4))) unsigned short u16x4;
typedef __attribute__((ext_vector_type(8))) unsigned short u16x8;
typedef __attribute__((ext_vector_type(4))) unsigned int u32x4;

__device__ inline unsigned short f2bf(float f) {
    unsigned int u;
    __builtin_memcpy(&u, &f, 4);
    u += 0x7fffu + ((u >> 16) & 1u);
    return (unsigned short)(u >> 16);
}

__device__ inline f32x4 mfma16(bf16x8 a, bf16x8 b, f32x4 c) {
    return __builtin_amdgcn_mfma_f32_16x16x32_bf16(a, b, c, 0, 0, 0);
}
__device__ inline f32x16 mfma32(bf16x8 a, bf16x8 b, f32x16 c) {
    return __builtin_amdgcn_mfma_f32_32x32x16_bf16(a, b, c, 0, 0, 0);
}

__device__ inline void gl16(const unsigned short* g, unsigned short* l) {
    __builtin_amdgcn_global_load_lds(
        (const __attribute__((address_space(1))) unsigned int*)g,
        (__attribute__((address_space(3))) unsigned int*)l,
        16, 0, 0);
}

__device__ inline unsigned cvtpk(float lo, float hi) {
    unsigned r;
    asm("v_cvt_pk_bf16_f32 %0, %1, %2" : "=v"(r) : "v"(lo), "v"(hi));
    return r;
}

// ---------------------------------------------------------------------------
// Kernel 0: f32 -> bf16 conversion of x and the four weight matrices.
// ---------------------------------------------------------------------------
__global__ __launch_bounds__(256) void convert_bf16(
    const float* __restrict__ x,
    const float* __restrict__ wq, const float* __restrict__ wk,
    const float* __restrict__ wv, const float* __restrict__ wo,
    unsigned short* __restrict__ xb,
    unsigned short* __restrict__ wqb, unsigned short* __restrict__ wkb,
    unsigned short* __restrict__ wvb, unsigned short* __restrict__ wob)
{
    int cid = blockIdx.x * 256 + threadIdx.x;
    #pragma unroll
    for (int it = 0; it < 4; ++it, cid += 262144) {
        const float* src;
        unsigned short* dst;
        size_t off;
        if (cid < 524288) {
            src = x; dst = xb; off = (size_t)cid * 8;
        } else {
            const int t = cid - 524288;
            const int seg = t >> 17;
            off = (size_t)(t & 131071) * 8;
            src = seg == 0 ? wq : seg == 1 ? wk : seg == 2 ? wv : wo;
            dst = seg == 0 ? wqb : seg == 1 ? wkb : seg == 2 ? wvb : wob;
        }
        f32x4 a = *(const f32x4*)(src + off);
        f32x4 b = *(const f32x4*)(src + off + 4);
        u32x4 v = { cvtpk(a[0], a[1]), cvtpk(a[2], a[3]),
                    cvtpk(b[0], b[1]), cvtpk(b[2], b[3]) };
        *(u32x4*)(dst + off) = v;
    }
}

// ---------------------------------------------------------------------------
// Kernel 1: QKV projections with prefetch-overlap 2-phase (T3/T4-lite):
// per K-step: vmcnt(0)+barrier -> ds_read frags to regs -> lgkmcnt(0)+barrier
// -> issue NEXT tile's gl16 -> 32 MFMA. Next-tile loads fly under compute.
// ---------------------------------------------------------------------------
__global__ __launch_bounds__(256) void qkv_bf16(
    const unsigned short* __restrict__ xb,
    const unsigned short* __restrict__ wqb, const unsigned short* __restrict__ wkb,
    const unsigned short* __restrict__ wvb,
    unsigned short* __restrict__ qfr, unsigned short* __restrict__ kfr,
    unsigned short* __restrict__ vfr)
{
    __shared__ unsigned short sR[128 * 64];
    __shared__ unsigned short sL[128 * 64];

    const int z = blockIdx.z;
    const unsigned short* W = (z == 0) ? wqb : (z == 1) ? wkb : wvb;
    const unsigned short* Rs = (z < 2) ? xb : W;
    const unsigned short* Ls = (z < 2) ? W : xb;
    const int rblk = (z < 2) ? blockIdx.x : blockIdx.y;
    const int lblk = (z < 2) ? blockIdx.y : blockIdx.x;

    const int tid = threadIdx.x;
    const int l = tid & 63, w = tid >> 6;
    const int lrow = l & 15, koff4 = (l >> 4) * 4;
    const int swz = lrow & 7;
    const int wrow = (w >> 1) * 64, wcol = (w & 1) * 64;

    f32x4 acc[4][4] = {};

    const int srow = w * 32 + (l >> 3);
    const int scol = ((l & 7) ^ ((l >> 3) & 7)) * 8;
    const unsigned short* gR = Rs + (size_t)(rblk * 128 + srow) * 1024 + scol;
    const unsigned short* gL = Ls + (size_t)(lblk * 128 + srow) * 1024 + scol;
    unsigned short* lRb = sR + (w * 32) * 64;
    unsigned short* lLb = sL + (w * 32) * 64;

    auto stage = [&](int kk) {
        #pragma unroll
        for (int p = 0; p < 4; ++p) {
            gl16(gR + (size_t)p * 8 * 1024 + kk, lRb + p * 512);
            gl16(gL + (size_t)p * 8 * 1024 + kk, lLb + p * 512);
        }
    };

    stage(0);
    for (int kk = 0; kk < 1024; kk += 64) {
        asm volatile("s_waitcnt vmcnt(0)" ::: "memory");     // this tile landed (per-wave)
        __builtin_amdgcn_s_barrier();                        // all waves landed
        __builtin_amdgcn_sched_barrier(0);

        bf16x8 aL[2][4], bR[2][4];
        #pragma unroll
        for (int kt = 0; kt < 2; ++kt)
            #pragma unroll
            for (int f = 0; f < 4; ++f) {
                const int co = ((kt * 4 + (l >> 4)) ^ swz) * 8;
                aL[kt][f] = *(const bf16x8*)&sL[(wcol + f * 16 + lrow) * 64 + co];
                bR[kt][f] = *(const bf16x8*)&sR[(wrow + f * 16 + lrow) * 64 + co];
            }
        asm volatile("s_waitcnt lgkmcnt(0)" ::: "memory");   // frags in regs
        __builtin_amdgcn_sched_barrier(0);
        __builtin_amdgcn_s_barrier();                        // all waves done reading LDS
        __builtin_amdgcn_sched_barrier(0);

        if (kk + 64 < 1024) stage(kk + 64);                  // overlaps with MFMAs below

        __builtin_amdgcn_s_setprio(1);
        #pragma unroll
        for (int kt = 0; kt < 2; ++kt)
            #pragma unroll
            for (int af = 0; af < 4; ++af)
                #pragma unroll
                for (int bf = 0; bf < 4; ++bf)
                    acc[af][bf] = mfma16(aL[kt][af], bR[kt][bf], acc[af][bf]);
        __builtin_amdgcn_s_setprio(0);
    }

    #pragma unroll
    for (int af = 0; af < 4; ++af) {
        #pragma unroll
        for (int bf = 0; bf < 4; ++bf) {
            const int m = rblk * 128 + wrow + bf * 16 + lrow;
            const int n0 = lblk * 128 + wcol + af * 16 + koff4;
            f32x4 v = acc[af][bf];
            unsigned p0 = cvtpk(v[0], v[1]), p1 = cvtpk(v[2], v[3]);
            u16x4 val = { (unsigned short)(p0 & 0xffff), (unsigned short)(p0 >> 16),
                          (unsigned short)(p1 & 0xffff), (unsigned short)(p1 >> 16) };
            if (z < 2) {
                const int bq = m >> 11, s = m & 2047;
                const int h2 = n0 >> 6, dd = n0 & 63;
                const size_t addr = (size_t)((bq * 16 + h2) * 64 + (s >> 5)) * 2048
                                  + (size_t)(dd >> 4) * 512 + (size_t)((dd >> 3) & 1) * 256
                                  + (size_t)(s & 31) * 8 + (dd & 7);
                unsigned short* dst = z ? kfr : qfr;
                *(u16x4*)(dst + addr) = val;
            } else {
                const int h2 = m >> 6, dd = m & 63;
                const int bq = n0 >> 11, t = n0 & 2047;
                const size_t addr = (size_t)((bq * 16 + h2) * 64 + (t >> 5)) * 2048
                                  + (size_t)((dd >> 5) * 2 + ((t >> 4) & 1)) * 512
                                  + (size_t)((t >> 3) & 1) * 256
                                  + (size_t)(dd & 31) * 8 + (t & 7);
                *(u16x4*)(vfr + addr) = val;
            }
        }
    }
}

// ---------------------------------------------------------------------------
// Kernel 2: retention, 2-tiles-per-wave K/V sharing. Block = 4 waves on the
// tile PAIR (2pr, 2pr+1) of one (b,h): both tiles' s-windows nearly coincide,
// so each loaded K/V block feeds 16 MFMAs (2 QK + 2 PV chains) instead of 8 —
// loads halve, per-load stall amortizes 2x, ILP doubles. 4-wave s-chunked,
// register ping-pong, two-phase deterministic LDS reduce. R10 head->XCD map.
// ---------------------------------------------------------------------------
__global__ __launch_bounds__(256) void retention_twin(
    const unsigned short* __restrict__ qfr, const unsigned short* __restrict__ kfr,
    const unsigned short* __restrict__ vfr, const float* __restrict__ gammas,
    unsigned short* __restrict__ ret)
{
    __shared__ float red[3][32][64];   // 24 KB, two sequential reduce phases

    const int bid = blockIdx.x;
    const int xcd = bid & 7;
    const int r_ = bid >> 3;                 // 0..127
    const int pr = 31 - (r_ >> 2);           // pair index, heavy first
    const int m = r_ & 3;                    // head slot on this XCD
    const int tA = pr << 1, tB = tA + 1;
    const int b = m >> 1;
    const int pi = b ? (7 - xcd) : xcd;
    const int h = (m & 1) ? (15 - pi) : pi;
    const float lg = log2f(gammas[h]);       // < 0
    const int cut_i = (int)(45.0f / (-lg));
    const float gi32 = exp2f(-32.0f * lg);   // gamma^-32
    const float g32 = exp2f(32.0f * lg);     // gamma^+32

    const int tid = threadIdx.x;
    const int l = tid & 63, w = tid >> 6;
    const int l31 = l & 31, hi = l >> 5;
    const int tA0 = tA << 5, tB0 = tB << 5;
    const int tqA = tA0 + l31;

    const size_t hbase = (size_t)((b * 16 + h) * 64) * 2048;
    const unsigned short* qfb = qfr + hbase + l * 8;
    const unsigned short* kfb = kfr + hbase + l * 8;
    const unsigned short* vfb = vfr + hbase + l * 8;

    // Q fragments for BOTH tiles (B operand: n=l31 -> t)
    bf16x8 qfA[4], qfB[4];
    #pragma unroll
    for (int kt = 0; kt < 4; ++kt) {
        qfA[kt] = *(const bf16x8*)(qfb + (size_t)tA * 2048 + kt * 512);
        qfB[kt] = *(const bf16x8*)(qfb + (size_t)tB * 2048 + kt * 512);
    }

    // cf[r] = gamma^(31 - crow(r)), crow = (r&3)+4*hi+8*(r>>2)  (same both tiles)
    float cf[16];
    #pragma unroll
    for (int r = 0; r < 16; ++r) {
        const int crow = (r & 3) + (hi << 2) + ((r >> 2) << 3);
        cf[r] = exp2f((float)(31 - crow) * lg);
    }

    int lo = tA0 - 31 - cut_i;
    lo = (lo <= 0) ? 0 : (lo >> 5);

    const int n = tB - lo + 1;               // union window incl. tB
    const int chunk = (n + 3) >> 2;
    const int my_lo = lo + w * chunk;
    int my_hi = my_lo + chunk;
    if (my_hi > tB + 1) my_hi = tB + 1;

    f32x16 aA0 = {}, aA1 = {}, aB0 = {}, aB1 = {};

    if (my_lo < my_hi) {
        float rowfA = 0.125f * exp2f((float)(tqA - (my_lo << 5) - 31) * lg);

        bf16x8 k1[4], v1[4], k2[4], v2[4];

        auto load = [&](int sb, bf16x8* kf, bf16x8* vf) {
            const unsigned short* kp = kfb + (size_t)sb * 2048;
            const unsigned short* vp = vfb + (size_t)sb * 2048;
            #pragma unroll
            for (int kt = 0; kt < 4; ++kt) kf[kt] = *(const bf16x8*)(kp + kt * 512);
            #pragma unroll
            for (int i = 0; i < 4; ++i) vf[i] = *(const bf16x8*)(vp + i * 512);
        };

        auto compute = [&](const bf16x8* kc, const bf16x8* vc, int sb) {
            const bool hasA = (sb <= tA);
            f32x16 scA = {}, scB = {};
            __builtin_amdgcn_s_setprio(1);
            if (hasA) {
                #pragma unroll
                for (int kt = 0; kt < 4; ++kt) scA = mfma32(kc[kt], qfA[kt], scA);
            }
            #pragma unroll
            for (int kt = 0; kt < 4; ++kt) scB = mfma32(kc[kt], qfB[kt], scB);
            __builtin_amdgcn_s_setprio(0);

            const float rowfB = rowfA * g32;
            if (hasA) {
                float wv_[16];
                if (sb == tA) {
                    #pragma unroll
                    for (int r = 0; r < 16; ++r) {
                        const int crow = (r & 3) + (hi << 2) + ((r >> 2) << 3);
                        float t_ = scA[r] * rowfA * cf[r];
                        wv_[r] = (l31 >= crow) ? t_ : 0.0f;
                    }
                } else {
                    #pragma unroll
                    for (int r = 0; r < 16; ++r) wv_[r] = scA[r] * rowfA * cf[r];
                }
                unsigned pk_[8];
                #pragma unroll
                for (int i = 0; i < 8; ++i) pk_[i] = cvtpk(wv_[2 * i], wv_[2 * i + 1]);
                asm("v_permlane32_swap_b32 %0, %1" : "+v"(pk_[0]), "+v"(pk_[2]));
                asm("v_permlane32_swap_b32 %0, %1" : "+v"(pk_[1]), "+v"(pk_[3]));
                asm("v_permlane32_swap_b32 %0, %1" : "+v"(pk_[4]), "+v"(pk_[6]));
                asm("v_permlane32_swap_b32 %0, %1" : "+v"(pk_[5]), "+v"(pk_[7]));
                u32x4 f0v = { pk_[0], pk_[1], pk_[2], pk_[3] };
                u32x4 f1v = { pk_[4], pk_[5], pk_[6], pk_[7] };
                const bf16x8 pa0 = __builtin_bit_cast(bf16x8, f0v);
                const bf16x8 pa1 = __builtin_bit_cast(bf16x8, f1v);
                __builtin_amdgcn_s_setprio(1);
                aA0 = mfma32(pa0, vc[0], aA0);
                aA0 = mfma32(pa1, vc[1], aA0);
                aA1 = mfma32(pa0, vc[2], aA1);
                aA1 = mfma32(pa1, vc[3], aA1);
                __builtin_amdgcn_s_setprio(0);
            }
            {
                float wv_[16];
                if (sb == tB) {
                    #pragma unroll
                    for (int r = 0; r < 16; ++r) {
                        const int crow = (r & 3) + (hi << 2) + ((r >> 2) << 3);
                        float t_ = scB[r] * rowfB * cf[r];
                        wv_[r] = (l31 >= crow) ? t_ : 0.0f;
                    }
                } else {
                    #pragma unroll
                    for (int r = 0; r < 16; ++r) wv_[r] = scB[r] * rowfB * cf[r];
                }
                unsigned pk_[8];
                #pragma unroll
                for (int i = 0; i < 8; ++i) pk_[i] = cvtpk(wv_[2 * i], wv_[2 * i + 1]);
                asm("v_permlane32_swap_b32 %0, %1" : "+v"(pk_[0]), "+v"(pk_[2]));
                asm("v_permlane32_swap_b32 %0, %1" : "+v"(pk_[1]), "+v"(pk_[3]));
                asm("v_permlane32_swap_b32 %0, %1" : "+v"(pk_[4]), "+v"(pk_[6]));
                asm("v_permlane32_swap_b32 %0, %1" : "+v"(pk_[5]), "+v"(pk_[7]));
                u32x4 f0v = { pk_[0], pk_[1], pk_[2], pk_[3] };
                u32x4 f1v = { pk_[4], pk_[5], pk_[6], pk_[7] };
                const bf16x8 pb0 = __builtin_bit_cast(bf16x8, f0v);
                const bf16x8 pb1 = __builtin_bit_cast(bf16x8, f1v);
                __builtin_amdgcn_s_setprio(1);
                aB0 = mfma32(pb0, vc[0], aB0);
                aB0 = mfma32(pb1, vc[1], aB0);
                aB1 = mfma32(pb0, vc[2], aB1);
                aB1 = mfma32(pb1, vc[3], aB1);
                __builtin_amdgcn_s_setprio(0);
            }
            rowfA *= gi32;
        };

        int sb = my_lo;
        load(sb, k1, v1);
        while (true) {
            const bool more1 = (sb + 1 < my_hi);
            if (more1) load(sb + 1, k2, v2);
            compute(k1, v1, sb);
            ++sb;
            if (!more1) break;
            const bool more2 = (sb + 1 < my_hi);
            if (more2) load(sb + 1, k1, v1);
            compute(k2, v2, sb);
            ++sb;
            if (!more2) break;
        }
    }

    // two-phase deterministic reduce: tile A then tile B
    #pragma unroll
    for (int phase = 0; phase < 2; ++phase) {
        const f32x16& p0 = phase ? aB0 : aA0;
        const f32x16& p1 = phase ? aB1 : aA1;
        const int t0 = phase ? tB0 : tA0;
        if (w > 0) {
            #pragma unroll
            for (int r = 0; r < 16; ++r) {
                red[w - 1][r][l]      = p0[r];
                red[w - 1][r + 16][l] = p1[r];
            }
        }
        __syncthreads();
        if (w == 0) {
            f32x16 s0 = p0, s1 = p1;
            #pragma unroll
            for (int jj = 0; jj < 3; ++jj)
                #pragma unroll
                for (int r = 0; r < 16; ++r) {
                    s0[r] += red[jj][r][l];
                    s1[r] += red[jj][r + 16][l];
                }
            #pragma unroll
            for (int r = 0; r < 16; ++r) {
                const int tl = (r & 3) + (hi << 2) + ((r >> 2) << 3);
                unsigned short* dst = ret + (size_t)(b * 2048 + t0 + tl) * 1024 + h * 64 + l31;
                dst[0]  = f2bf(s0[r]);
                dst[32] = f2bf(s1[r]);
            }
        }
        __syncthreads();
    }
}

// ---------------------------------------------------------------------------
// Kernel 3: out = ret @ wo.T, prefetch-overlap 2-phase (same as qkv).
// ---------------------------------------------------------------------------
__global__ __launch_bounds__(256) void out_bf16(
    const unsigned short* __restrict__ ret, const unsigned short* __restrict__ wob,
    float* __restrict__ out)
{
    __shared__ unsigned short sR[128 * 64];
    __shared__ unsigned short sL[128 * 64];

    const int rblk = blockIdx.x;
    const int lblk = blockIdx.y;

    const int tid = threadIdx.x;
    const int l = tid & 63, w = tid >> 6;
    const int lrow = l & 15, koff4 = (l >> 4) * 4;
    const int swz = lrow & 7;
    const int wrow = (w >> 1) * 64, wcol = (w & 1) * 64;

    f32x4 acc[4][4] = {};

    const int srow = w * 32 + (l >> 3);
    const int scol = ((l & 7) ^ ((l >> 3) & 7)) * 8;
    const unsigned short* gR = ret + (size_t)(rblk * 128 + srow) * 1024 + scol;
    const unsigned short* gL = wob + (size_t)(lblk * 128 + srow) * 1024 + scol;
    unsigned short* lRb = sR + (w * 32) * 64;
    unsigned short* lLb = sL + (w * 32) * 64;

    auto stage = [&](int kk) {
        #pragma unroll
        for (int p = 0; p < 4; ++p) {
            gl16(gR + (size_t)p * 8 * 1024 + kk, lRb + p * 512);
            gl16(gL + (size_t)p * 8 * 1024 + kk, lLb + p * 512);
        }
    };

    stage(0);
    for (int kk = 0; kk < 1024; kk += 64) {
        asm volatile("s_waitcnt vmcnt(0)" ::: "memory");
        __builtin_amdgcn_s_barrier();
        __builtin_amdgcn_sched_barrier(0);

        bf16x8 aL[2][4], bR[2][4];
        #pragma unroll
        for (int kt = 0; kt < 2; ++kt)
            #pragma unroll
            for (int f = 0; f < 4; ++f) {
                const int co = ((kt * 4 + (l >> 4)) ^ swz) * 8;
                aL[kt][f] = *(const bf16x8*)&sL[(wcol + f * 16 + lrow) * 64 + co];
                bR[kt][f] = *(const bf16x8*)&sR[(wrow + f * 16 + lrow) * 64 + co];
            }
        asm volatile("s_waitcnt lgkmcnt(0)" ::: "memory");
        __builtin_amdgcn_sched_barrier(0);
        __builtin_amdgcn_s_barrier();
        __builtin_amdgcn_sched_barrier(0);

        if (kk + 64 < 1024) stage(kk + 64);

        __builtin_amdgcn_s_setprio(1);
        #pragma unroll
        for (int kt = 0; kt < 2; ++kt)
            #pragma unroll
            for (int af = 0; af < 4; ++af)
                #pragma unroll
                for (int bf = 0; bf < 4; ++bf)
                    acc[af][bf] = mfma16(aL[kt][af], bR[kt][bf], acc[af][bf]);
        __builtin_amdgcn_s_setprio(0);
    }

    #pragma unroll
    for (int af = 0; af < 4; ++af)
        #pragma unroll
        for (int bf = 0; bf < 4; ++bf) {
            const int m = rblk * 128 + wrow + bf * 16 + lrow;
            const int n0 = lblk * 128 + wcol + af * 16 + koff4;
            *(f32x4*)(out + (size_t)m * 1024 + n0) = acc[af][bf];
        }
}

extern "C" void kernel_launch(void* const* d_in, const int* in_sizes, int n_in,
                              void* d_out, int out_size, void* d_ws, size_t ws_size,
                              hipStream_t stream) {
    const float* x      = (const float*)d_in[0];
    const float* wq     = (const float*)d_in[1];
    const float* wk     = (const float*)d_in[2];
    const float* wv     = (const float*)d_in[3];
    const float* wo     = (const float*)d_in[4];
    const float* gammas = (const float*)d_in[5];
    float* out = (float*)d_out;

    unsigned short* ws = (unsigned short*)d_ws;
    unsigned short* qf  = ws;
    unsigned short* kf  = ws + (size_t)4 * 1024 * 1024;
    unsigned short* vf  = ws + (size_t)8 * 1024 * 1024;
    unsigned short* ret = ws + (size_t)12 * 1024 * 1024;   // also xb (dead after qkv)
    unsigned short* xb  = ret;
    unsigned short* wqb = ws + (size_t)16 * 1024 * 1024;
    unsigned short* wkb = ws + (size_t)17 * 1024 * 1024;
    unsigned short* wvb = ws + (size_t)18 * 1024 * 1024;
    unsigned short* wob = ws + (size_t)19 * 1024 * 1024;

    convert_bf16<<<1024, 256, 0, stream>>>(x, wq, wk, wv, wo, xb, wqb, wkb, wvb, wob);
    qkv_bf16<<<dim3(32, 8, 3), 256, 0, stream>>>(xb, wqb, wkb, wvb, qf, kf, vf);
    retention_twin<<<1024, 256, 0, stream>>>(qf, kf, vf, gammas, ret);
    out_bf16<<<dim3(32, 8), 256, 0, stream>>>(ret, wob, out);
}

// Round 14
// 92.109 us; speedup vs baseline: 1.1520x; 1.0511x over previous
//
#include <hip/hip_runtime.h>

// MultiScaleRetention on MI355X (gfx950)
// B=2, L=2048, D=1024, H=16, hd=64. fp32 in/out, bf16 MFMA internally.
//
// ws layout (ushort elems), 40 MB total:
//   qf[4M] | kf[4M] | vf[4M] | ret/xb[4M] (aliased) | wqb|wkb|wvb|wob [1M each]
//   qf,kf: fragment-linear [(b*16+h)*64+sb][kt:4][lane:64][8]
//   vf:    fragment-linear [(b*16+h)*64+sb][i:4][lane:64][8]
//   ret,xb: [B*L][1024] row-major bf16

typedef __attribute__((ext_vector_type(8))) short bf16x8;
typedef __attribute__((ext_vector_type(4))) float f32x4;
typedef __attribute__((ext_vector_type(16))) float f32x16;
typedef __attribute__((ext_vector_type(4))) unsigned short u16x4;
typedef __attribute__((ext_vector_type(8))) unsigned short u16x8;
typedef __attribute__((ext_vector_type(4))) unsigned int u32x4;

__device__ inline unsigned short f2bf(float f) {
    unsigned int u;
    __builtin_memcpy(&u, &f, 4);
    u += 0x7fffu + ((u >> 16) & 1u);
    return (unsigned short)(u >> 16);
}

__device__ inline f32x4 mfma16(bf16x8 a, bf16x8 b, f32x4 c) {
    return __builtin_amdgcn_mfma_f32_16x16x32_bf16(a, b, c, 0, 0, 0);
}
__device__ inline f32x16 mfma32(bf16x8 a, bf16x8 b, f32x16 c) {
    return __builtin_amdgcn_mfma_f32_32x32x16_bf16(a, b, c, 0, 0, 0);
}

__device__ inline void gl16(const unsigned short* g, unsigned short* l) {
    __builtin_amdgcn_global_load_lds(
        (const __attribute__((address_space(1))) unsigned int*)g,
        (__attribute__((address_space(3))) unsigned int*)l,
        16, 0, 0);
}

__device__ inline unsigned cvtpk(float lo, float hi) {
    unsigned r;
    asm("v_cvt_pk_bf16_f32 %0, %1, %2" : "=v"(r) : "v"(lo), "v"(hi));
    return r;
}

// ---------------------------------------------------------------------------
// Kernel 0: f32 -> bf16 conversion of x and the four weight matrices.
// ---------------------------------------------------------------------------
__global__ __launch_bounds__(256) void convert_bf16(
    const float* __restrict__ x,
    const float* __restrict__ wq, const float* __restrict__ wk,
    const float* __restrict__ wv, const float* __restrict__ wo,
    unsigned short* __restrict__ xb,
    unsigned short* __restrict__ wqb, unsigned short* __restrict__ wkb,
    unsigned short* __restrict__ wvb, unsigned short* __restrict__ wob)
{
    int cid = blockIdx.x * 256 + threadIdx.x;
    #pragma unroll
    for (int it = 0; it < 4; ++it, cid += 262144) {
        const float* src;
        unsigned short* dst;
        size_t off;
        if (cid < 524288) {
            src = x; dst = xb; off = (size_t)cid * 8;
        } else {
            const int t = cid - 524288;
            const int seg = t >> 17;
            off = (size_t)(t & 131071) * 8;
            src = seg == 0 ? wq : seg == 1 ? wk : seg == 2 ? wv : wo;
            dst = seg == 0 ? wqb : seg == 1 ? wkb : seg == 2 ? wvb : wob;
        }
        f32x4 a = *(const f32x4*)(src + off);
        f32x4 b = *(const f32x4*)(src + off + 4);
        u32x4 v = { cvtpk(a[0], a[1]), cvtpk(a[2], a[3]),
                    cvtpk(b[0], b[1]), cvtpk(b[2], b[3]) };
        *(u32x4*)(dst + off) = v;
    }
}

// ---------------------------------------------------------------------------
// Kernel 1: QKV projections with prefetch-overlap 2-phase (R13, kept):
// per K-step: vmcnt(0)+barrier -> ds_read frags to regs -> lgkmcnt(0)+barrier
// -> issue NEXT tile's gl16 -> 32 MFMA. Next-tile loads fly under compute.
// NO gamma folding (that was R12's regression).
// ---------------------------------------------------------------------------
__global__ __launch_bounds__(256) void qkv_bf16(
    const unsigned short* __restrict__ xb,
    const unsigned short* __restrict__ wqb, const unsigned short* __restrict__ wkb,
    const unsigned short* __restrict__ wvb,
    unsigned short* __restrict__ qfr, unsigned short* __restrict__ kfr,
    unsigned short* __restrict__ vfr)
{
    __shared__ unsigned short sR[128 * 64];
    __shared__ unsigned short sL[128 * 64];

    const int z = blockIdx.z;
    const unsigned short* W = (z == 0) ? wqb : (z == 1) ? wkb : wvb;
    const unsigned short* Rs = (z < 2) ? xb : W;
    const unsigned short* Ls = (z < 2) ? W : xb;
    const int rblk = (z < 2) ? blockIdx.x : blockIdx.y;
    const int lblk = (z < 2) ? blockIdx.y : blockIdx.x;

    const int tid = threadIdx.x;
    const int l = tid & 63, w = tid >> 6;
    const int lrow = l & 15, koff4 = (l >> 4) * 4;
    const int swz = lrow & 7;
    const int wrow = (w >> 1) * 64, wcol = (w & 1) * 64;

    f32x4 acc[4][4] = {};

    const int srow = w * 32 + (l >> 3);
    const int scol = ((l & 7) ^ ((l >> 3) & 7)) * 8;
    const unsigned short* gR = Rs + (size_t)(rblk * 128 + srow) * 1024 + scol;
    const unsigned short* gL = Ls + (size_t)(lblk * 128 + srow) * 1024 + scol;
    unsigned short* lRb = sR + (w * 32) * 64;
    unsigned short* lLb = sL + (w * 32) * 64;

    auto stage = [&](int kk) {
        #pragma unroll
        for (int p = 0; p < 4; ++p) {
            gl16(gR + (size_t)p * 8 * 1024 + kk, lRb + p * 512);
            gl16(gL + (size_t)p * 8 * 1024 + kk, lLb + p * 512);
        }
    };

    stage(0);
    for (int kk = 0; kk < 1024; kk += 64) {
        asm volatile("s_waitcnt vmcnt(0)" ::: "memory");     // this tile landed (per-wave)
        __builtin_amdgcn_s_barrier();                        // all waves landed
        __builtin_amdgcn_sched_barrier(0);

        bf16x8 aL[2][4], bR[2][4];
        #pragma unroll
        for (int kt = 0; kt < 2; ++kt)
            #pragma unroll
            for (int f = 0; f < 4; ++f) {
                const int co = ((kt * 4 + (l >> 4)) ^ swz) * 8;
                aL[kt][f] = *(const bf16x8*)&sL[(wcol + f * 16 + lrow) * 64 + co];
                bR[kt][f] = *(const bf16x8*)&sR[(wrow + f * 16 + lrow) * 64 + co];
            }
        asm volatile("s_waitcnt lgkmcnt(0)" ::: "memory");   // frags in regs
        __builtin_amdgcn_sched_barrier(0);
        __builtin_amdgcn_s_barrier();                        // all waves done reading LDS
        __builtin_amdgcn_sched_barrier(0);

        if (kk + 64 < 1024) stage(kk + 64);                  // overlaps with MFMAs below

        __builtin_amdgcn_s_setprio(1);
        #pragma unroll
        for (int kt = 0; kt < 2; ++kt)
            #pragma unroll
            for (int af = 0; af < 4; ++af)
                #pragma unroll
                for (int bf = 0; bf < 4; ++bf)
                    acc[af][bf] = mfma16(aL[kt][af], bR[kt][bf], acc[af][bf]);
        __builtin_amdgcn_s_setprio(0);
    }

    #pragma unroll
    for (int af = 0; af < 4; ++af) {
        #pragma unroll
        for (int bf = 0; bf < 4; ++bf) {
            const int m = rblk * 128 + wrow + bf * 16 + lrow;
            const int n0 = lblk * 128 + wcol + af * 16 + koff4;
            f32x4 v = acc[af][bf];
            unsigned p0 = cvtpk(v[0], v[1]), p1 = cvtpk(v[2], v[3]);
            u16x4 val = { (unsigned short)(p0 & 0xffff), (unsigned short)(p0 >> 16),
                          (unsigned short)(p1 & 0xffff), (unsigned short)(p1 >> 16) };
            if (z < 2) {
                const int bq = m >> 11, s = m & 2047;
                const int h2 = n0 >> 6, dd = n0 & 63;
                const size_t addr = (size_t)((bq * 16 + h2) * 64 + (s >> 5)) * 2048
                                  + (size_t)(dd >> 4) * 512 + (size_t)((dd >> 3) & 1) * 256
                                  + (size_t)(s & 31) * 8 + (dd & 7);
                unsigned short* dst = z ? kfr : qfr;
                *(u16x4*)(dst + addr) = val;
            } else {
                const int h2 = m >> 6, dd = m & 63;
                const int bq = n0 >> 11, t = n0 & 2047;
                const size_t addr = (size_t)((bq * 16 + h2) * 64 + (t >> 5)) * 2048
                                  + (size_t)((dd >> 5) * 2 + ((t >> 4) & 1)) * 512
                                  + (size_t)((t >> 3) & 1) * 256
                                  + (size_t)(dd & 31) * 8 + (t & 7);
                *(u16x4*)(vfr + addr) = val;
            }
        }
    }
}

// ---------------------------------------------------------------------------
// Kernel 2: retention with per-wave async LDS pipeline (R12 structure, cf[]
// multiply restored in-kernel). Block = 4 waves on one (bh,tw); wave w owns a
// contiguous quarter of the s-window, staging K/V via global_load_lds into a
// PRIVATE LDS double-buffer; counted s_waitcnt vmcnt(8) keeps the next stage
// in flight. Final reduce reuses the staging LDS after a barrier.
// ---------------------------------------------------------------------------
__global__ __launch_bounds__(256) void retention_lds(
    const unsigned short* __restrict__ qfr, const unsigned short* __restrict__ kfr,
    const unsigned short* __restrict__ vfr, const float* __restrict__ gammas,
    unsigned short* __restrict__ ret)
{
    __shared__ unsigned short kv[4][2][4096];   // [wave][buf][K:2048|V:2048] = 64 KB

    const int bid = blockIdx.x;
    const int xcd = bid & 7;
    const int r_ = bid >> 3;                     // 0..255
    const int p = r_ >> 2;                       // 0..63, heavy tiles first
    const int m = ((r_ & 3) + (r_ >> 5)) & 3;    // bijective; cycles heads per CU
    const int tw = 63 - p;
    const int b = m >> 1;
    const int pi = b ? (7 - xcd) : xcd;
    const int h = (m & 1) ? (15 - pi) : pi;
    const float lg = log2f(gammas[h]);           // < 0
    const int cut_i = (int)(45.0f / (-lg));
    const float gi32 = exp2f(-32.0f * lg);       // gamma^-32

    const int tid = threadIdx.x;
    const int l = tid & 63, w = tid >> 6;
    const int l31 = l & 31, hi = l >> 5;
    const int tw0 = tw << 5;
    const int tq = tw0 + l31;

    const size_t hbase = (size_t)((b * 16 + h) * 64) * 2048;
    const unsigned short* qfb = qfr + hbase + l * 8;
    const unsigned short* kfb = kfr + hbase + l * 8;
    const unsigned short* vfb = vfr + hbase + l * 8;

    // Q fragments (B operand: n=l31 -> t)
    bf16x8 qf[4];
    #pragma unroll
    for (int kt = 0; kt < 4; ++kt)
        qf[kt] = *(const bf16x8*)(qfb + (size_t)tw * 2048 + kt * 512);

    // cf[r] = gamma^(31 - crow(r)), crow = (r&3)+4*hi+8*(r>>2)
    float cf[16];
    #pragma unroll
    for (int r = 0; r < 16; ++r) {
        const int crow = (r & 3) + (hi << 2) + ((r >> 2) << 3);
        cf[r] = exp2f((float)(31 - crow) * lg);
    }

    int sb_lo = tw0 - 31 - cut_i;
    sb_lo = (sb_lo <= 0) ? 0 : (sb_lo >> 5);

    const int n = tw - sb_lo + 1;
    const int chunk = (n + 3) >> 2;
    const int my_lo = sb_lo + w * chunk;
    int my_hi = my_lo + chunk;
    if (my_hi > tw + 1) my_hi = tw + 1;

    unsigned short* slot[2] = { &kv[w][0][0], &kv[w][1][0] };

    auto stage = [&](int sb, unsigned short* s) {
        const unsigned short* kp = kfb + (size_t)sb * 2048;
        const unsigned short* vp = vfb + (size_t)sb * 2048;
        #pragma unroll
        for (int t = 0; t < 4; ++t) gl16(kp + t * 512, s + t * 512);
        #pragma unroll
        for (int t = 0; t < 4; ++t) gl16(vp + t * 512, s + 2048 + t * 512);
    };

    f32x16 acc0 = {}, acc1 = {};

    if (my_lo < my_hi) {
        float rowf = 0.125f * exp2f((float)(tq - (my_lo << 5) - 31) * lg);
        stage(my_lo, slot[0]);
        if (my_lo + 1 < my_hi) stage(my_lo + 1, slot[1]);

        for (int sb = my_lo; sb < my_hi; ++sb) {
            unsigned short* cur = slot[(sb - my_lo) & 1];
            // counted wait: stage(sb) done; stage(sb+1) stays in flight
            if (sb + 1 < my_hi) asm volatile("s_waitcnt vmcnt(8)" ::: "memory");
            else                asm volatile("s_waitcnt vmcnt(0)" ::: "memory");
            __builtin_amdgcn_sched_barrier(0);

            bf16x8 kc[4], vc[4];
            #pragma unroll
            for (int kt = 0; kt < 4; ++kt)
                kc[kt] = *(const bf16x8*)(cur + kt * 512 + l * 8);
            #pragma unroll
            for (int i = 0; i < 4; ++i)
                vc[i] = *(const bf16x8*)(cur + 2048 + i * 512 + l * 8);

            // QK^T swapped: A=K (m=s), B=Q (n=t). D: col=t=l31, row=s=crow(r)
            f32x16 sc = {};
            __builtin_amdgcn_s_setprio(1);
            #pragma unroll
            for (int kt = 0; kt < 4; ++kt) sc = mfma32(kc[kt], qf[kt], sc);
            __builtin_amdgcn_s_setprio(0);

            float wv_[16];
            if (sb == tw) {            // wave-uniform: diag tile
                const int dtq = tq - (sb << 5);
                #pragma unroll
                for (int r = 0; r < 16; ++r) {
                    const int crow = (r & 3) + (hi << 2) + ((r >> 2) << 3);
                    float t_ = sc[r] * rowf * cf[r];
                    wv_[r] = (dtq >= crow) ? t_ : 0.0f;
                }
            } else {
                #pragma unroll
                for (int r = 0; r < 16; ++r)
                    wv_[r] = sc[r] * rowf * cf[r];
            }
            unsigned pk_[8];
            #pragma unroll
            for (int i = 0; i < 8; ++i) pk_[i] = cvtpk(wv_[2 * i], wv_[2 * i + 1]);
            asm("v_permlane32_swap_b32 %0, %1" : "+v"(pk_[0]), "+v"(pk_[2]));
            asm("v_permlane32_swap_b32 %0, %1" : "+v"(pk_[1]), "+v"(pk_[3]));
            asm("v_permlane32_swap_b32 %0, %1" : "+v"(pk_[4]), "+v"(pk_[6]));
            asm("v_permlane32_swap_b32 %0, %1" : "+v"(pk_[5]), "+v"(pk_[7]));
            u32x4 f0v = { pk_[0], pk_[1], pk_[2], pk_[3] };
            u32x4 f1v = { pk_[4], pk_[5], pk_[6], pk_[7] };
            const bf16x8 pa0 = __builtin_bit_cast(bf16x8, f0v);
            const bf16x8 pa1 = __builtin_bit_cast(bf16x8, f1v);
            // PV: A=P (m=t), B=V (n=d, k=s)
            __builtin_amdgcn_s_setprio(1);
            acc0 = mfma32(pa0, vc[0], acc0);
            acc0 = mfma32(pa1, vc[1], acc0);
            acc1 = mfma32(pa0, vc[2], acc1);
            acc1 = mfma32(pa1, vc[3], acc1);
            __builtin_amdgcn_s_setprio(0);
            rowf *= gi32;

            // restage current slot with sb+2 (after all LDS reads drained)
            if (sb + 2 < my_hi) {
                asm volatile("s_waitcnt lgkmcnt(0)" ::: "memory");
                __builtin_amdgcn_sched_barrier(0);
                stage(sb + 2, cur);
            }
        }
    }

    // reduce: reuse kv LDS as float scratch (all gl16 drained before loop exit)
    __syncthreads();
    float* red = (float*)&kv[0][0][0];   // need 24 KB of the 64 KB
    if (w > 0) {
        #pragma unroll
        for (int r = 0; r < 16; ++r) {
            red[(w - 1) * 2048 + r * 64 + l]        = acc0[r];
            red[(w - 1) * 2048 + (r + 16) * 64 + l] = acc1[r];
        }
    }
    __syncthreads();
    if (w == 0) {
        #pragma unroll
        for (int jj = 0; jj < 3; ++jj)
            #pragma unroll
            for (int r = 0; r < 16; ++r) {
                acc0[r] += red[jj * 2048 + r * 64 + l];
                acc1[r] += red[jj * 2048 + (r + 16) * 64 + l];
            }
        #pragma unroll
        for (int r = 0; r < 16; ++r) {
            const int tl = (r & 3) + (hi << 2) + ((r >> 2) << 3);
            unsigned short* dst = ret + (size_t)(b * 2048 + tw0 + tl) * 1024 + h * 64 + l31;
            dst[0]  = f2bf(acc0[r]);
            dst[32] = f2bf(acc1[r]);
        }
    }
}

// ---------------------------------------------------------------------------
// Kernel 3: out = ret @ wo.T, prefetch-overlap 2-phase (R13, kept).
// ---------------------------------------------------------------------------
__global__ __launch_bounds__(256) void out_bf16(
    const unsigned short* __restrict__ ret, const unsigned short* __restrict__ wob,
    float* __restrict__ out)
{
    __shared__ unsigned short sR[128 * 64];
    __shared__ unsigned short sL[128 * 64];

    const int rblk = blockIdx.x;
    const int lblk = blockIdx.y;

    const int tid = threadIdx.x;
    const int l = tid & 63, w = tid >> 6;
    const int lrow = l & 15, koff4 = (l >> 4) * 4;
    const int swz = lrow & 7;
    const int wrow = (w >> 1) * 64, wcol = (w & 1) * 64;

    f32x4 acc[4][4] = {};

    const int srow = w * 32 + (l >> 3);
    const int scol = ((l & 7) ^ ((l >> 3) & 7)) * 8;
    const unsigned short* gR = ret + (size_t)(rblk * 128 + srow) * 1024 + scol;
    const unsigned short* gL = wob + (size_t)(lblk * 128 + srow) * 1024 + scol;
    unsigned short* lRb = sR + (w * 32) * 64;
    unsigned short* lLb = sL + (w * 32) * 64;

    auto stage = [&](int kk) {
        #pragma unroll
        for (int p = 0; p < 4; ++p) {
            gl16(gR + (size_t)p * 8 * 1024 + kk, lRb + p * 512);
            gl16(gL + (size_t)p * 8 * 1024 + kk, lLb + p * 512);
        }
    };

    stage(0);
    for (int kk = 0; kk < 1024; kk += 64) {
        asm volatile("s_waitcnt vmcnt(0)" ::: "memory");
        __builtin_amdgcn_s_barrier();
        __builtin_amdgcn_sched_barrier(0);

        bf16x8 aL[2][4], bR[2][4];
        #pragma unroll
        for (int kt = 0; kt < 2; ++kt)
            #pragma unroll
            for (int f = 0; f < 4; ++f) {
                const int co = ((kt * 4 + (l >> 4)) ^ swz) * 8;
                aL[kt][f] = *(const bf16x8*)&sL[(wcol + f * 16 + lrow) * 64 + co];
                bR[kt][f] = *(const bf16x8*)&sR[(wrow + f * 16 + lrow) * 64 + co];
            }
        asm volatile("s_waitcnt lgkmcnt(0)" ::: "memory");
        __builtin_amdgcn_sched_barrier(0);
        __builtin_amdgcn_s_barrier();
        __builtin_amdgcn_sched_barrier(0);

        if (kk + 64 < 1024) stage(kk + 64);

        __builtin_amdgcn_s_setprio(1);
        #pragma unroll
        for (int kt = 0; kt < 2; ++kt)
            #pragma unroll
            for (int af = 0; af < 4; ++af)
                #pragma unroll
                for (int bf = 0; bf < 4; ++bf)
                    acc[af][bf] = mfma16(aL[kt][af], bR[kt][bf], acc[af][bf]);
        __builtin_amdgcn_s_setprio(0);
    }

    #pragma unroll
    for (int af = 0; af < 4; ++af)
        #pragma unroll
        for (int bf = 0; bf < 4; ++bf) {
            const int m = rblk * 128 + wrow + bf * 16 + lrow;
            const int n0 = lblk * 128 + wcol + af * 16 + koff4;
            *(f32x4*)(out + (size_t)m * 1024 + n0) = acc[af][bf];
        }
}

extern "C" void kernel_launch(void* const* d_in, const int* in_sizes, int n_in,
                              void* d_out, int out_size, void* d_ws, size_t ws_size,
                              hipStream_t stream) {
    const float* x      = (const float*)d_in[0];
    const float* wq     = (const float*)d_in[1];
    const float* wk     = (const float*)d_in[2];
    const float* wv     = (const float*)d_in[3];
    const float* wo     = (const float*)d_in[4];
    const float* gammas = (const float*)d_in[5];
    float* out = (float*)d_out;

    unsigned short* ws = (unsigned short*)d_ws;
    unsigned short* qf  = ws;
    unsigned short* kf  = ws + (size_t)4 * 1024 * 1024;
    unsigned short* vf  = ws + (size_t)8 * 1024 * 1024;
    unsigned short* ret = ws + (size_t)12 * 1024 * 1024;   // also xb (dead after qkv)
    unsigned short* xb  = ret;
    unsigned short* wqb = ws + (size_t)16 * 1024 * 1024;
    unsigned short* wkb = ws + (size_t)17 * 1024 * 1024;
    unsigned short* wvb = ws + (size_t)18 * 1024 * 1024;
    unsigned short* wob = ws + (size_t)19 * 1024 * 1024;

    convert_bf16<<<1024, 256, 0, stream>>>(x, wq, wk, wv, wo, xb, wqb, wkb, wvb, wob);
    qkv_bf16<<<dim3(32, 8, 3), 256, 0, stream>>>(xb, wqb, wkb, wvb, qf, kf, vf);
    retention_lds<<<2048, 256, 0, stream>>>(qf, kf, vf, gammas, ret);
    out_bf16<<<dim3(32, 8), 256, 0, stream>>>(ret, wob, out);
}